// Round 1
// baseline (305.829 us; speedup 1.0000x reference)
//
#include <hip/hip_runtime.h>
#include <math.h>

#define GROUPS 4
#define DCH    64
#define NBATCH 32
#define CTOT   256
#define HW     3136
#define CHW    (CTOT*HW)        /* 802816 */
#define MTOT   (NBATCH*HW)      /* 100352 */
#define PB     128              /* partial blocks per group */
#define CB     (MTOT/PB)        /* 784 columns per block */
#define SPB    (HW/CB)          /* 4 sub-blocks per sample */
#define EPSV   1e-5f

// ---------------------------------------------------------------------------
// K1: per-group partial Gram (64x64) + per-channel partial sums.
// LDS tile uses 16B-granule XOR swizzle: granule g' = g ^ ((d>>2)&7)
// so both store phase (lanes along c) and read phase (lanes along e, step 4)
// spread across all 8 granule bank-groups.
// ---------------------------------------------------------------------------
__global__ __launch_bounds__(256) void k1_gram(const float* __restrict__ X,
                                               float* __restrict__ pGram,
                                               float* __restrict__ pSum)
{
    const int pb  = blockIdx.x;
    const int g   = blockIdx.y;
    const int tid = threadIdx.x;
    const int n   = pb / SPB;
    const int s0  = (pb % SPB) * CB;
    const float* base = X + (size_t)n * CHW + (size_t)g * DCH * HW + s0;

    __shared__ float tile[4096];   // [d][granule-swizzled 64 floats]
    __shared__ float sacc[1024];   // [d][16]

    float acc[4][4];
#pragma unroll
    for (int i = 0; i < 4; ++i)
#pragma unroll
        for (int j = 0; j < 4; ++j) acc[i][j] = 0.f;
    float4 sv[4];
#pragma unroll
    for (int i = 0; i < 4; ++i) sv[i] = make_float4(0.f, 0.f, 0.f, 0.f);

    const int d0 = (tid >> 4) << 2;
    const int e0 = (tid & 15) << 2;
    const int swzd = (d0 >> 2) & 7;
    const int swze = (e0 >> 2) & 7;

    const int NT = (CB + 63) >> 6;   // 13 tiles (12 full + 16-col tail)
    for (int t = 0; t < NT; ++t) {
        const int c0 = t << 6;
        __syncthreads();   // previous compute done before overwrite
#pragma unroll
        for (int i = 0; i < 4; ++i) {
            int flat = (i << 8) + tid;
            int d    = flat >> 4;
            int gq   = flat & 15;
            int c    = c0 + (gq << 2);
            float4 v = make_float4(0.f, 0.f, 0.f, 0.f);
            if (c < CB) v = *reinterpret_cast<const float4*>(base + d * HW + c);
            sv[i].x += v.x; sv[i].y += v.y; sv[i].z += v.z; sv[i].w += v.w;
            int phys = gq ^ ((d >> 2) & 7);
            *reinterpret_cast<float4*>(&tile[(d << 6) + (phys << 2)]) = v;
        }
        __syncthreads();
#pragma unroll
        for (int k0 = 0; k0 < 16; ++k0) {
            float4 Ad[4], Ae[4];
#pragma unroll
            for (int j = 0; j < 4; ++j) {
                Ad[j] = *reinterpret_cast<const float4*>(
                    &tile[((d0 + j) << 6) + ((k0 ^ swzd) << 2)]);
                Ae[j] = *reinterpret_cast<const float4*>(
                    &tile[((e0 + j) << 6) + ((k0 ^ swze) << 2)]);
            }
#pragma unroll
            for (int i = 0; i < 4; ++i) {
#pragma unroll
                for (int j = 0; j < 4; ++j) {
                    acc[i][j] += Ad[i].x * Ae[j].x + Ad[i].y * Ae[j].y
                               + Ad[i].z * Ae[j].z + Ad[i].w * Ae[j].w;
                }
            }
        }
    }

    // write partial Gram
    float* pg = pGram + ((size_t)g * PB + pb) * 4096;
#pragma unroll
    for (int i = 0; i < 4; ++i) {
        float4 v = make_float4(acc[i][0], acc[i][1], acc[i][2], acc[i][3]);
        *reinterpret_cast<float4*>(pg + ((d0 + i) << 6) + e0) = v;
    }

    // per-channel partial sums
    __syncthreads();
#pragma unroll
    for (int i = 0; i < 4; ++i) {
        int flat = (i << 8) + tid;
        int d = flat >> 4, gq = flat & 15;
        sacc[(d << 4) + gq] = sv[i].x + sv[i].y + sv[i].z + sv[i].w;
    }
    __syncthreads();
    if (tid < 64) {
        float s = 0.f;
#pragma unroll
        for (int q = 0; q < 16; ++q) s += sacc[(tid << 4) + q];
        pSum[((size_t)g * PB + pb) * 64 + tid] = s;
    }
}

// ---------------------------------------------------------------------------
// K2a: reduce partials -> Gram[g][4096], Mean[g][64]
// ---------------------------------------------------------------------------
__global__ __launch_bounds__(256) void k2a_reduce(const float* __restrict__ pGram,
                                                  const float* __restrict__ pSum,
                                                  float* __restrict__ Gram,
                                                  float* __restrict__ Mean)
{
    const int cb = blockIdx.x;   // 0..63 (chunk of 64 Gram entries)
    const int g  = blockIdx.y;
    const int tid = threadIdx.x;
    const int e = tid & 63, q = tid >> 6;
    __shared__ float red[4][64];
    __shared__ float red2[4][64];

    const float* pg = pGram + (size_t)g * PB * 4096 + cb * 64 + e;
    float s = 0.f;
    for (int pb = q * (PB / 4); pb < (q + 1) * (PB / 4); ++pb)
        s += pg[(size_t)pb * 4096];
    red[q][e] = s;
    if (cb == 0) {
        const float* ps = pSum + (size_t)g * PB * 64 + e;
        float s2 = 0.f;
        for (int pb = q * (PB / 4); pb < (q + 1) * (PB / 4); ++pb)
            s2 += ps[pb * 64];
        red2[q][e] = s2;
    }
    __syncthreads();
    if (tid < 64) {
        Gram[g * 4096 + cb * 64 + tid] =
            red[0][tid] + red[1][tid] + red[2][tid] + red[3][tid];
        if (cb == 0)
            Mean[g * 64 + tid] =
                (red2[0][tid] + red2[1][tid] + red2[2][tid] + red2[3][tid]) *
                (1.0f / (float)MTOT);
    }
}

// ---------------------------------------------------------------------------
// K2b: Sigma -> trace-normalize -> 5 Newton-Schulz iters -> A' and offset
// All matrices in LDS [64][68] (rows 16B-aligned). 4x4 register tiles.
// MODE 0: C = A*B.  MODE 1: C = 1.5*C - 0.5*A*B.
// ---------------------------------------------------------------------------
template <int MODE>
__device__ __forceinline__ void mm64(float* __restrict__ C,
                                     const float* __restrict__ A,
                                     const float* __restrict__ B,
                                     int i0, int j0)
{
    float acc[4][4];
#pragma unroll
    for (int i = 0; i < 4; ++i)
#pragma unroll
        for (int j = 0; j < 4; ++j) acc[i][j] = 0.f;

    for (int k0 = 0; k0 < 64; k0 += 4) {
        float4 a[4], b[4];
#pragma unroll
        for (int i = 0; i < 4; ++i)
            a[i] = *reinterpret_cast<const float4*>(A + (i0 + i) * 68 + k0);
#pragma unroll
        for (int kk = 0; kk < 4; ++kk)
            b[kk] = *reinterpret_cast<const float4*>(B + (k0 + kk) * 68 + j0);
#pragma unroll
        for (int i = 0; i < 4; ++i) {
            acc[i][0] += a[i].x * b[0].x + a[i].y * b[1].x + a[i].z * b[2].x + a[i].w * b[3].x;
            acc[i][1] += a[i].x * b[0].y + a[i].y * b[1].y + a[i].z * b[2].y + a[i].w * b[3].y;
            acc[i][2] += a[i].x * b[0].z + a[i].y * b[1].z + a[i].z * b[2].z + a[i].w * b[3].z;
            acc[i][3] += a[i].x * b[0].w + a[i].y * b[1].w + a[i].z * b[2].w + a[i].w * b[3].w;
        }
    }
#pragma unroll
    for (int i = 0; i < 4; ++i) {
        float4 outv = make_float4(acc[i][0], acc[i][1], acc[i][2], acc[i][3]);
        if (MODE == 1) {
            float4 oldv = *reinterpret_cast<const float4*>(C + (i0 + i) * 68 + j0);
            outv.x = 1.5f * oldv.x - 0.5f * outv.x;
            outv.y = 1.5f * oldv.y - 0.5f * outv.y;
            outv.z = 1.5f * oldv.z - 0.5f * outv.z;
            outv.w = 1.5f * oldv.w - 0.5f * outv.w;
        }
        *reinterpret_cast<float4*>(C + (i0 + i) * 68 + j0) = outv;
    }
}

__global__ __launch_bounds__(256) void k2b_ns(const float* __restrict__ Gram,
                                              const float* __restrict__ Mean,
                                              const float* __restrict__ Wt,
                                              const float* __restrict__ Bs,
                                              float* __restrict__ Aout,
                                              float* __restrict__ Off)
{
    const int g   = blockIdx.x;
    const int tid = threadIdx.x;
    __shared__ float Sn[64 * 68];
    __shared__ float Pm[64 * 68];
    __shared__ float T1[64 * 68];
    __shared__ float T2[64 * 68];
    __shared__ float lmean[64];
    __shared__ float redm[1024];
    __shared__ float rtr_s;

    if (tid < 64) lmean[tid] = Mean[g * 64 + tid];
    __syncthreads();
    for (int idx = tid; idx < 4096; idx += 256) {
        int d = idx >> 6, e = idx & 63;
        float v = Gram[g * 4096 + idx] * (1.0f / (float)MTOT) - lmean[d] * lmean[e];
        if (d == e) v += EPSV;
        Sn[d * 68 + e] = v;
        Pm[d * 68 + e] = (d == e) ? 1.f : 0.f;
    }
    __syncthreads();
    if (tid < 64) {
        float v = Sn[tid * 68 + tid];
#pragma unroll
        for (int off = 32; off > 0; off >>= 1) v += __shfl_down(v, off);
        if (tid == 0) rtr_s = 1.f / v;
    }
    __syncthreads();
    const float rTr = rtr_s;
    for (int idx = tid; idx < 4096; idx += 256) {
        int d = idx >> 6, e = idx & 63;
        Sn[d * 68 + e] *= rTr;
    }
    __syncthreads();

    const int i0 = (tid >> 4) << 2, j0 = (tid & 15) << 2;
    for (int it = 0; it < 5; ++it) {
        mm64<0>(T1, Pm, Pm, i0, j0); __syncthreads();
        mm64<0>(T2, T1, Pm, i0, j0); __syncthreads();
        mm64<1>(Pm, T2, Sn, i0, j0); __syncthreads();
    }

    // A'[d][e] = weight[c]*sqrt(rTr)*P[d][e];  off[d] = bias[c] - A'[d]·mean
    const float sc = sqrtf(rTr);
#pragma unroll
    for (int i = 0; i < 4; ++i) {
        int d = i0 + i;
        float w = Wt[g * 64 + d] * sc;
        float4 v;
        v.x = Pm[d * 68 + j0 + 0] * w;
        v.y = Pm[d * 68 + j0 + 1] * w;
        v.z = Pm[d * 68 + j0 + 2] * w;
        v.w = Pm[d * 68 + j0 + 3] * w;
        *reinterpret_cast<float4*>(Aout + g * 4096 + (d << 6) + j0) = v;
        redm[(d << 4) + (tid & 15)] =
            v.x * lmean[j0] + v.y * lmean[j0 + 1] + v.z * lmean[j0 + 2] + v.w * lmean[j0 + 3];
    }
    __syncthreads();
    if (tid < 64) {
        float s = 0.f;
#pragma unroll
        for (int q = 0; q < 16; ++q) s += redm[(tid << 4) + q];
        Off[g * 64 + tid] = Bs[g * 64 + tid] - s;
    }
}

// ---------------------------------------------------------------------------
// K3: out[c][col] = sum_e A'[d][e]*x[e][col] + off[d]
// Thread holds the 64-channel column in VGPRs; A' read as uniform-address
// float4 broadcasts from LDS (conflict-free).
// ---------------------------------------------------------------------------
__global__ __launch_bounds__(256) void k3_apply(const float* __restrict__ X,
                                                const float* __restrict__ Aout,
                                                const float* __restrict__ Off,
                                                float* __restrict__ Y)
{
    const int chunk = blockIdx.x;   // 0..97, 1024 columns each
    const int g     = blockIdx.y;
    const int tid   = threadIdx.x;
    __shared__ float lA[4096];
    __shared__ float loff[64];
    for (int idx = tid; idx < 4096; idx += 256) lA[idx] = Aout[g * 4096 + idx];
    if (tid < 64) loff[tid] = Off[g * 64 + tid];
    __syncthreads();

#pragma unroll 1
    for (int p = 0; p < 4; ++p) {
        const int col = chunk * 1024 + p * 256 + tid;
        const int n = col / HW;
        const int s = col - n * HW;
        const float* bp = X + (size_t)n * CHW + (size_t)g * DCH * HW + s;
        float x[64];
#pragma unroll
        for (int e = 0; e < 64; ++e) x[e] = bp[e * HW];
        float* op = Y + (size_t)n * CHW + (size_t)g * DCH * HW + s;
#pragma unroll 4
        for (int d = 0; d < 64; ++d) {
            float accv = loff[d];
            const float4* arow = reinterpret_cast<const float4*>(lA + (d << 6));
#pragma unroll
            for (int e4 = 0; e4 < 16; ++e4) {
                float4 a = arow[e4];
                accv += a.x * x[4 * e4] + a.y * x[4 * e4 + 1]
                      + a.z * x[4 * e4 + 2] + a.w * x[4 * e4 + 3];
            }
            op[d * HW] = accv;
        }
    }
}

// ---------------------------------------------------------------------------
extern "C" void kernel_launch(void* const* d_in, const int* in_sizes, int n_in,
                              void* d_out, int out_size, void* d_ws, size_t ws_size,
                              hipStream_t stream)
{
    const float* X  = (const float*)d_in[0];
    const float* Wt = (const float*)d_in[1];
    const float* Bs = (const float*)d_in[2];
    float* Y  = (float*)d_out;
    float* ws = (float*)d_ws;

    // workspace layout (floats)
    float* pGram = ws;                                   // 4*PB*4096
    float* pSum  = pGram + (size_t)4 * PB * 4096;        // 4*PB*64
    float* Gram  = pSum  + (size_t)4 * PB * 64;          // 4*4096
    float* Mean  = Gram  + 4 * 4096;                     // 256
    float* Aout  = Mean  + 256;                          // 4*4096
    float* Off   = Aout  + 4 * 4096;                     // 256

    k1_gram  <<<dim3(PB, GROUPS), 256, 0, stream>>>(X, pGram, pSum);
    k2a_reduce<<<dim3(64, GROUPS), 256, 0, stream>>>(pGram, pSum, Gram, Mean);
    k2b_ns   <<<dim3(GROUPS), 256, 0, stream>>>(Gram, Mean, Wt, Bs, Aout, Off);
    k3_apply <<<dim3(98, GROUPS), 256, 0, stream>>>(X, Aout, Off, Y);
}

// Round 2
// 296.329 us; speedup vs baseline: 1.0321x; 1.0321x over previous
//
#include <hip/hip_runtime.h>
#include <math.h>

#define GROUPS 4
#define DCH    64
#define NBATCH 32
#define CTOT   256
#define HW     3136
#define CHW    (CTOT*HW)        /* 802816 */
#define MTOT   (NBATCH*HW)      /* 100352 */
#define PB     112              /* partial k-blocks per group */
#define KPB    (MTOT/PB)        /* 896 cols per block */
#define EPSV   1e-5f

typedef __attribute__((ext_vector_type(8))) short bf16x8;
typedef __attribute__((ext_vector_type(4))) float f32x4;

__device__ __forceinline__ f32x4 mfma16(bf16x8 a, bf16x8 b, f32x4 c) {
    return __builtin_amdgcn_mfma_f32_16x16x32_bf16(a, b, c, 0, 0, 0);
}

// truncation split: x = hi + lo (exact), bf16(hi), bf16(lo); err <= 2^-16 |x|
__device__ __forceinline__ void split2(float x, short& h, short& l) {
    union { float f; unsigned u; } c; c.f = x;
    h = (short)(c.u >> 16);
    union { unsigned u; float f; } hm; hm.u = c.u & 0xFFFF0000u;
    union { float f; unsigned u; } lo; lo.f = x - hm.f;
    l = (short)(lo.u >> 16);
}

// ---------------------------------------------------------------------------
// K1: per-group partial Gram via bf16 hi/lo split MFMA, fragments straight
// from global (k = spatial cols -> per-lane k-runs are memory-contiguous).
// 8 waves: tile-row (w&3) x k-parity (w>>2). No LDS in main loop.
// ---------------------------------------------------------------------------
__global__ __launch_bounds__(512, 4) void k1_gram(const float* __restrict__ X,
                                                  float* __restrict__ pGram,
                                                  float* __restrict__ pSum)
{
    const int pb   = blockIdx.x;        // 0..PB-1
    const int g    = blockIdx.y;
    const int tid  = threadIdx.x;       // 0..511
    const int w    = tid >> 6;
    const int lane = tid & 63;
    const int tr   = w & 3;             // tile-row (A row-block)
    const int par  = w >> 2;            // k parity
    const int lr   = lane & 15;
    const int q    = lane >> 4;

    __shared__ float lg[2][4096];
    __shared__ float rsum[2][64][4];

    f32x4 acc[4];
#pragma unroll
    for (int c = 0; c < 4; ++c) acc[c] = (f32x4)(0.f);
    float sum4[4] = {0.f, 0.f, 0.f, 0.f};

    const float* Xg = X + (size_t)g * DCH * HW;

    for (int t = 0; t < 14; ++t) {
        const int kk = pb * KPB + (2 * t + par) * 32;   // kstep start col
        const int n  = kk / HW;                          // never crosses sample
        const int s  = kk - n * HW;
        const float* bp = Xg + (size_t)n * CHW + s + q * 8;

        float xv[4][8];
#pragma unroll
        for (int b = 0; b < 4; ++b) {
            const float* rp = bp + (size_t)(16 * b + lr) * HW;
            float4 v0 = *reinterpret_cast<const float4*>(rp);
            float4 v1 = *reinterpret_cast<const float4*>(rp + 4);
            xv[b][0] = v0.x; xv[b][1] = v0.y; xv[b][2] = v0.z; xv[b][3] = v0.w;
            xv[b][4] = v1.x; xv[b][5] = v1.y; xv[b][6] = v1.z; xv[b][7] = v1.w;
        }
#pragma unroll
        for (int b = 0; b < 4; ++b) {
#pragma unroll
            for (int j = 0; j < 8; ++j) sum4[b] += xv[b][j];
        }
        bf16x8 fh[4], fl[4];
#pragma unroll
        for (int b = 0; b < 4; ++b) {
#pragma unroll
            for (int j = 0; j < 8; ++j) {
                short h, l; split2(xv[b][j], h, l);
                fh[b][j] = h; fl[b][j] = l;
            }
        }
#pragma unroll
        for (int c = 0; c < 4; ++c) {
            acc[c] = mfma16(fh[tr], fh[c], acc[c]);
            acc[c] = mfma16(fh[tr], fl[c], acc[c]);
            acc[c] = mfma16(fl[tr], fh[c], acc[c]);
        }
    }

    // parity-split reduce in LDS
#pragma unroll
    for (int c = 0; c < 4; ++c) {
#pragma unroll
        for (int r = 0; r < 4; ++r) {
            int row = 16 * tr + 4 * q + r;
            int col = 16 * c + lr;
            lg[par][row * 64 + col] = acc[c][r];
        }
    }
    if (tr == 0) {
#pragma unroll
        for (int b = 0; b < 4; ++b) rsum[par][16 * b + lr][q] = sum4[b];
    }
    __syncthreads();

    float* pg = pGram + ((size_t)g * PB + pb) * 4096;
    for (int i = tid; i < 4096; i += 512) pg[i] = lg[0][i] + lg[1][i];
    if (tid < 64) {
        float s = 0.f;
#pragma unroll
        for (int qq = 0; qq < 4; ++qq) s += rsum[0][tid][qq] + rsum[1][tid][qq];
        pSum[((size_t)g * PB + pb) * 64 + tid] = s;
    }
}

// ---------------------------------------------------------------------------
// K2a: reduce partials -> Gram[g][4096], Mean[g][64]
// ---------------------------------------------------------------------------
__global__ __launch_bounds__(256) void k2a_reduce(const float* __restrict__ pGram,
                                                  const float* __restrict__ pSum,
                                                  float* __restrict__ Gram,
                                                  float* __restrict__ Mean)
{
    const int cb = blockIdx.x;   // 0..63
    const int g  = blockIdx.y;
    const int tid = threadIdx.x;
    const int e = tid & 63, q = tid >> 6;
    __shared__ float red[4][64];
    __shared__ float red2[4][64];

    const float* pg = pGram + (size_t)g * PB * 4096 + cb * 64 + e;
    float s = 0.f;
    for (int pb = q * (PB / 4); pb < (q + 1) * (PB / 4); ++pb)
        s += pg[(size_t)pb * 4096];
    red[q][e] = s;
    if (cb == 0) {
        const float* ps = pSum + (size_t)g * PB * 64 + e;
        float s2 = 0.f;
        for (int pb = q * (PB / 4); pb < (q + 1) * (PB / 4); ++pb)
            s2 += ps[pb * 64];
        red2[q][e] = s2;
    }
    __syncthreads();
    if (tid < 64) {
        Gram[g * 4096 + cb * 64 + tid] =
            red[0][tid] + red[1][tid] + red[2][tid] + red[3][tid];
        if (cb == 0)
            Mean[g * 64 + tid] =
                (red2[0][tid] + red2[1][tid] + red2[2][tid] + red2[3][tid]) *
                (1.0f / (float)MTOT);
    }
}

// ---------------------------------------------------------------------------
// K2b: Sigma -> trace-normalize -> 5 Newton-Schulz iters -> A' and offset
// (unchanged fp32 LDS version; optimize next round once measured)
// ---------------------------------------------------------------------------
template <int MODE>
__device__ __forceinline__ void mm64(float* __restrict__ C,
                                     const float* __restrict__ A,
                                     const float* __restrict__ B,
                                     int i0, int j0)
{
    float acc[4][4];
#pragma unroll
    for (int i = 0; i < 4; ++i)
#pragma unroll
        for (int j = 0; j < 4; ++j) acc[i][j] = 0.f;

    for (int k0 = 0; k0 < 64; k0 += 4) {
        float4 a[4], b[4];
#pragma unroll
        for (int i = 0; i < 4; ++i)
            a[i] = *reinterpret_cast<const float4*>(A + (i0 + i) * 68 + k0);
#pragma unroll
        for (int kk = 0; kk < 4; ++kk)
            b[kk] = *reinterpret_cast<const float4*>(B + (k0 + kk) * 68 + j0);
#pragma unroll
        for (int i = 0; i < 4; ++i) {
            acc[i][0] += a[i].x * b[0].x + a[i].y * b[1].x + a[i].z * b[2].x + a[i].w * b[3].x;
            acc[i][1] += a[i].x * b[0].y + a[i].y * b[1].y + a[i].z * b[2].y + a[i].w * b[3].y;
            acc[i][2] += a[i].x * b[0].z + a[i].y * b[1].z + a[i].z * b[2].z + a[i].w * b[3].z;
            acc[i][3] += a[i].x * b[0].w + a[i].y * b[1].w + a[i].z * b[2].w + a[i].w * b[3].w;
        }
    }
#pragma unroll
    for (int i = 0; i < 4; ++i) {
        float4 outv = make_float4(acc[i][0], acc[i][1], acc[i][2], acc[i][3]);
        if (MODE == 1) {
            float4 oldv = *reinterpret_cast<const float4*>(C + (i0 + i) * 68 + j0);
            outv.x = 1.5f * oldv.x - 0.5f * outv.x;
            outv.y = 1.5f * oldv.y - 0.5f * outv.y;
            outv.z = 1.5f * oldv.z - 0.5f * outv.z;
            outv.w = 1.5f * oldv.w - 0.5f * outv.w;
        }
        *reinterpret_cast<float4*>(C + (i0 + i) * 68 + j0) = outv;
    }
}

__global__ __launch_bounds__(256) void k2b_ns(const float* __restrict__ Gram,
                                              const float* __restrict__ Mean,
                                              const float* __restrict__ Wt,
                                              const float* __restrict__ Bs,
                                              float* __restrict__ Aout,
                                              float* __restrict__ Off)
{
    const int g   = blockIdx.x;
    const int tid = threadIdx.x;
    __shared__ float Sn[64 * 68];
    __shared__ float Pm[64 * 68];
    __shared__ float T1[64 * 68];
    __shared__ float T2[64 * 68];
    __shared__ float lmean[64];
    __shared__ float redm[1024];
    __shared__ float rtr_s;

    if (tid < 64) lmean[tid] = Mean[g * 64 + tid];
    __syncthreads();
    for (int idx = tid; idx < 4096; idx += 256) {
        int d = idx >> 6, e = idx & 63;
        float v = Gram[g * 4096 + idx] * (1.0f / (float)MTOT) - lmean[d] * lmean[e];
        if (d == e) v += EPSV;
        Sn[d * 68 + e] = v;
        Pm[d * 68 + e] = (d == e) ? 1.f : 0.f;
    }
    __syncthreads();
    if (tid < 64) {
        float v = Sn[tid * 68 + tid];
#pragma unroll
        for (int off = 32; off > 0; off >>= 1) v += __shfl_down(v, off);
        if (tid == 0) rtr_s = 1.f / v;
    }
    __syncthreads();
    const float rTr = rtr_s;
    for (int idx = tid; idx < 4096; idx += 256) {
        int d = idx >> 6, e = idx & 63;
        Sn[d * 68 + e] *= rTr;
    }
    __syncthreads();

    const int i0 = (tid >> 4) << 2, j0 = (tid & 15) << 2;
    for (int it = 0; it < 5; ++it) {
        mm64<0>(T1, Pm, Pm, i0, j0); __syncthreads();
        mm64<0>(T2, T1, Pm, i0, j0); __syncthreads();
        mm64<1>(Pm, T2, Sn, i0, j0); __syncthreads();
    }

    const float sc = sqrtf(rTr);
#pragma unroll
    for (int i = 0; i < 4; ++i) {
        int d = i0 + i;
        float wv = Wt[g * 64 + d] * sc;
        float4 v;
        v.x = Pm[d * 68 + j0 + 0] * wv;
        v.y = Pm[d * 68 + j0 + 1] * wv;
        v.z = Pm[d * 68 + j0 + 2] * wv;
        v.w = Pm[d * 68 + j0 + 3] * wv;
        *reinterpret_cast<float4*>(Aout + g * 4096 + (d << 6) + j0) = v;
        redm[(d << 4) + (tid & 15)] =
            v.x * lmean[j0] + v.y * lmean[j0 + 1] + v.z * lmean[j0 + 2] + v.w * lmean[j0 + 3];
    }
    __syncthreads();
    if (tid < 64) {
        float s = 0.f;
#pragma unroll
        for (int qq = 0; qq < 16; ++qq) s += redm[(tid << 4) + qq];
        Off[g * 64 + tid] = Bs[g * 64 + tid] - s;
    }
}

// ---------------------------------------------------------------------------
// K3: out = A'(x) + off via hi/lo MFMA. A' fragments live in registers for
// the whole kernel; x fragments are 8 strided dword loads/lane (lanes 0..15
// cover a full 64B line). No LDS. HBM-bound.
// ---------------------------------------------------------------------------
__global__ __launch_bounds__(256) void k3_apply(const float* __restrict__ X,
                                                const float* __restrict__ Aout,
                                                const float* __restrict__ Off,
                                                float* __restrict__ Y)
{
    const int bx   = blockIdx.x;        // 0..447
    const int g    = blockIdx.y;
    const int tid  = threadIdx.x;
    const int w    = tid >> 6;          // d-block 16w
    const int lane = tid & 63;
    const int lr   = lane & 15;
    const int q    = lane >> 4;

    // A' fragments (2 ksteps x hi/lo), loaded once
    bf16x8 ah[2], al[2];
#pragma unroll
    for (int s = 0; s < 2; ++s) {
        const float* ap = Aout + g * 4096 + (16 * w + lr) * 64 + 32 * s + 8 * q;
        float4 v0 = *reinterpret_cast<const float4*>(ap);
        float4 v1 = *reinterpret_cast<const float4*>(ap + 4);
        float av[8] = {v0.x, v0.y, v0.z, v0.w, v1.x, v1.y, v1.z, v1.w};
#pragma unroll
        for (int j = 0; j < 8; ++j) {
            short h, l; split2(av[j], h, l);
            ah[s][j] = h; al[s][j] = l;
        }
    }
    float offv[4];
#pragma unroll
    for (int r = 0; r < 4; ++r) offv[r] = Off[g * 64 + 16 * w + 4 * q + r];

    const float* Xg = X + (size_t)g * DCH * HW;
    float*       Yg = Y + (size_t)g * DCH * HW;

    for (int c = bx; c < MTOT / 16; c += 448) {
        const int col0 = c * 16;            // 16-col chunk, never crosses sample
        const int n    = col0 / HW;
        const int s0   = col0 - n * HW;
        const float* base = Xg + (size_t)n * CHW + s0 + lr;

        f32x4 acc = (f32x4)(0.f);
#pragma unroll
        for (int ks = 0; ks < 2; ++ks) {
            const float* xp = base + (size_t)(32 * ks + 8 * q) * HW;
            float xv[8];
#pragma unroll
            for (int j = 0; j < 8; ++j) xv[j] = xp[(size_t)j * HW];
            bf16x8 bh, bl;
#pragma unroll
            for (int j = 0; j < 8; ++j) {
                short h, l; split2(xv[j], h, l);
                bh[j] = h; bl[j] = l;
            }
            acc = mfma16(ah[ks], bh, acc);
            acc = mfma16(ah[ks], bl, acc);
            acc = mfma16(al[ks], bh, acc);
        }
        float* yp = Yg + (size_t)n * CHW + s0 + lr;
#pragma unroll
        for (int r = 0; r < 4; ++r) {
            int row = 16 * w + 4 * q + r;
            yp[(size_t)row * HW] = acc[r] + offv[r];
        }
    }
}

// ---------------------------------------------------------------------------
extern "C" void kernel_launch(void* const* d_in, const int* in_sizes, int n_in,
                              void* d_out, int out_size, void* d_ws, size_t ws_size,
                              hipStream_t stream)
{
    const float* X  = (const float*)d_in[0];
    const float* Wt = (const float*)d_in[1];
    const float* Bs = (const float*)d_in[2];
    float* Y  = (float*)d_out;
    float* ws = (float*)d_ws;

    float* pGram = ws;                                   // 4*PB*4096
    float* pSum  = pGram + (size_t)4 * PB * 4096;        // 4*PB*64
    float* Gram  = pSum  + (size_t)4 * PB * 64;          // 4*4096
    float* Mean  = Gram  + 4 * 4096;                     // 256
    float* Aout  = Mean  + 256;                          // 4*4096
    float* Off   = Aout  + 4 * 4096;                     // 256

    k1_gram   <<<dim3(PB, GROUPS), 512, 0, stream>>>(X, pGram, pSum);
    k2a_reduce<<<dim3(64, GROUPS), 256, 0, stream>>>(pGram, pSum, Gram, Mean);
    k2b_ns    <<<dim3(GROUPS), 256, 0, stream>>>(Gram, Mean, Wt, Bs, Aout, Off);
    k3_apply  <<<dim3(448, GROUPS), 256, 0, stream>>>(X, Aout, Off, Y);
}

// Round 3
// 138.703 us; speedup vs baseline: 2.2049x; 2.1364x over previous
//
#include <hip/hip_runtime.h>
#include <math.h>

#define GROUPS 4
#define DCH    64
#define NBATCH 32
#define CTOT   256
#define HW     3136
#define CHW    (CTOT*HW)        /* 802816 */
#define MTOT   (NBATCH*HW)      /* 100352 */
#define PB     112              /* partial k-blocks per group */
#define KPB    (MTOT/PB)        /* 896 cols per block */
#define EPSV   1e-5f

typedef __attribute__((ext_vector_type(8))) short bf16x8;
typedef __attribute__((ext_vector_type(4))) float f32x4;

__device__ __forceinline__ f32x4 mfma16(bf16x8 a, bf16x8 b, f32x4 c) {
    return __builtin_amdgcn_mfma_f32_16x16x32_bf16(a, b, c, 0, 0, 0);
}

// truncation split: x = hi + lo (exact), bf16(hi), bf16(lo); err <= 2^-16 |x|
__device__ __forceinline__ void split2(float x, short& h, short& l) {
    union { float f; unsigned u; } c; c.f = x;
    h = (short)(c.u >> 16);
    union { unsigned u; float f; } hm; hm.u = c.u & 0xFFFF0000u;
    union { float f; unsigned u; } lo; lo.f = x - hm.f;
    l = (short)(lo.u >> 16);
}

// ---------------------------------------------------------------------------
// K1: per-group partial Gram via bf16 hi/lo split MFMA, fragments straight
// from global. 8 waves = 4 tile-rows x 2 k-parities. Per k-step: pack the
// wave's A-slab once (ah/al), then stream B-slabs one at a time (low VGPR
// pressure -> no spill; round-2's launch_bounds-forced 64 VGPR spilled).
// ---------------------------------------------------------------------------
__global__ __launch_bounds__(512) void k1_gram(const float* __restrict__ X,
                                               float* __restrict__ pGram,
                                               float* __restrict__ pSum)
{
    const int pb   = blockIdx.x;        // 0..PB-1
    const int g    = blockIdx.y;
    const int tid  = threadIdx.x;       // 0..511
    const int w    = tid >> 6;
    const int lane = tid & 63;
    const int tr   = w & 3;             // tile-row (A row-block)
    const int par  = w >> 2;            // k parity
    const int lr   = lane & 15;
    const int q    = lane >> 4;

    __shared__ float lg[2][4096];
    __shared__ float rsum[2][64];

    f32x4 acc[4];
#pragma unroll
    for (int c = 0; c < 4; ++c) acc[c] = (f32x4)(0.f);
    float sumv = 0.f;

    const float* Xg = X + (size_t)g * DCH * HW;

    for (int t = 0; t < 14; ++t) {
        const int kk = pb * KPB + (2 * t + par) * 32;   // 32-col k-step
        const int n  = kk / HW;                          // 3136%32==0: no crossing
        const int s  = kk - n * HW;
        const float* bp = Xg + (size_t)n * CHW + s + q * 8;

        // A slab: rows 16*tr..16*tr+15, this parity's 32 k-cols
        bf16x8 ah, al;
        {
            const float* rp = bp + (size_t)(16 * tr + lr) * HW;
            float4 v0 = *reinterpret_cast<const float4*>(rp);
            float4 v1 = *reinterpret_cast<const float4*>(rp + 4);
            float av[8] = {v0.x, v0.y, v0.z, v0.w, v1.x, v1.y, v1.z, v1.w};
#pragma unroll
            for (int j = 0; j < 8; ++j) {
                sumv += av[j];
                short h, l; split2(av[j], h, l);
                ah[j] = h; al[j] = l;
            }
        }
        // stream B slabs
#pragma unroll
        for (int c = 0; c < 4; ++c) {
            bf16x8 bh, bl;
            if (c == tr) {            // wave-uniform branch
                bh = ah; bl = al;
            } else {
                const float* rp = bp + (size_t)(16 * c + lr) * HW;
                float4 v0 = *reinterpret_cast<const float4*>(rp);
                float4 v1 = *reinterpret_cast<const float4*>(rp + 4);
                float bv[8] = {v0.x, v0.y, v0.z, v0.w, v1.x, v1.y, v1.z, v1.w};
#pragma unroll
                for (int j = 0; j < 8; ++j) {
                    short h, l; split2(bv[j], h, l);
                    bh[j] = h; bl[j] = l;
                }
            }
            acc[c] = mfma16(ah, bh, acc[c]);
            acc[c] = mfma16(ah, bl, acc[c]);
            acc[c] = mfma16(al, bh, acc[c]);
        }
    }

    // row sums: reduce over q-quarters (lanes ^16, ^32)
    sumv += __shfl_xor(sumv, 16);
    sumv += __shfl_xor(sumv, 32);
    if (q == 0) rsum[par][16 * tr + lr] = sumv;

    // parity-split Gram partial into LDS
#pragma unroll
    for (int c = 0; c < 4; ++c) {
#pragma unroll
        for (int r = 0; r < 4; ++r) {
            int row = 16 * tr + 4 * q + r;
            int col = 16 * c + lr;
            lg[par][row * 64 + col] = acc[c][r];
        }
    }
    __syncthreads();

    float* pg = pGram + ((size_t)g * PB + pb) * 4096;
    for (int i = tid; i < 4096; i += 512) pg[i] = lg[0][i] + lg[1][i];
    if (tid < 64)
        pSum[((size_t)g * PB + pb) * 64 + tid] = rsum[0][tid] + rsum[1][tid];
}

// ---------------------------------------------------------------------------
// K2a: reduce partials -> Gram[g][4096], Mean[g][64]
// ---------------------------------------------------------------------------
__global__ __launch_bounds__(256) void k2a_reduce(const float* __restrict__ pGram,
                                                  const float* __restrict__ pSum,
                                                  float* __restrict__ Gram,
                                                  float* __restrict__ Mean)
{
    const int cb = blockIdx.x;   // 0..63
    const int g  = blockIdx.y;
    const int tid = threadIdx.x;
    const int e = tid & 63, q = tid >> 6;
    __shared__ float red[4][64];
    __shared__ float red2[4][64];

    const float* pg = pGram + (size_t)g * PB * 4096 + cb * 64 + e;
    float s = 0.f;
    for (int pb = q * (PB / 4); pb < (q + 1) * (PB / 4); ++pb)
        s += pg[(size_t)pb * 4096];
    red[q][e] = s;
    if (cb == 0) {
        const float* ps = pSum + (size_t)g * PB * 64 + e;
        float s2 = 0.f;
        for (int pb = q * (PB / 4); pb < (q + 1) * (PB / 4); ++pb)
            s2 += ps[pb * 64];
        red2[q][e] = s2;
    }
    __syncthreads();
    if (tid < 64) {
        Gram[g * 4096 + cb * 64 + tid] =
            red[0][tid] + red[1][tid] + red[2][tid] + red[3][tid];
        if (cb == 0)
            Mean[g * 64 + tid] =
                (red2[0][tid] + red2[1][tid] + red2[2][tid] + red2[3][tid]) *
                (1.0f / (float)MTOT);
    }
}

// ---------------------------------------------------------------------------
// K2b: Sigma -> trace-normalize -> 5 Newton-Schulz iters -> A' and offset
// ---------------------------------------------------------------------------
template <int MODE>
__device__ __forceinline__ void mm64(float* __restrict__ C,
                                     const float* __restrict__ A,
                                     const float* __restrict__ B,
                                     int i0, int j0)
{
    float acc[4][4];
#pragma unroll
    for (int i = 0; i < 4; ++i)
#pragma unroll
        for (int j = 0; j < 4; ++j) acc[i][j] = 0.f;

    for (int k0 = 0; k0 < 64; k0 += 4) {
        float4 a[4], b[4];
#pragma unroll
        for (int i = 0; i < 4; ++i)
            a[i] = *reinterpret_cast<const float4*>(A + (i0 + i) * 68 + k0);
#pragma unroll
        for (int kk = 0; kk < 4; ++kk)
            b[kk] = *reinterpret_cast<const float4*>(B + (k0 + kk) * 68 + j0);
#pragma unroll
        for (int i = 0; i < 4; ++i) {
            acc[i][0] += a[i].x * b[0].x + a[i].y * b[1].x + a[i].z * b[2].x + a[i].w * b[3].x;
            acc[i][1] += a[i].x * b[0].y + a[i].y * b[1].y + a[i].z * b[2].y + a[i].w * b[3].y;
            acc[i][2] += a[i].x * b[0].z + a[i].y * b[1].z + a[i].z * b[2].z + a[i].w * b[3].z;
            acc[i][3] += a[i].x * b[0].w + a[i].y * b[1].w + a[i].z * b[2].w + a[i].w * b[3].w;
        }
    }
#pragma unroll
    for (int i = 0; i < 4; ++i) {
        float4 outv = make_float4(acc[i][0], acc[i][1], acc[i][2], acc[i][3]);
        if (MODE == 1) {
            float4 oldv = *reinterpret_cast<const float4*>(C + (i0 + i) * 68 + j0);
            outv.x = 1.5f * oldv.x - 0.5f * outv.x;
            outv.y = 1.5f * oldv.y - 0.5f * outv.y;
            outv.z = 1.5f * oldv.z - 0.5f * outv.z;
            outv.w = 1.5f * oldv.w - 0.5f * outv.w;
        }
        *reinterpret_cast<float4*>(C + (i0 + i) * 68 + j0) = outv;
    }
}

__global__ __launch_bounds__(256) void k2b_ns(const float* __restrict__ Gram,
                                              const float* __restrict__ Mean,
                                              const float* __restrict__ Wt,
                                              const float* __restrict__ Bs,
                                              float* __restrict__ Aout,
                                              float* __restrict__ Off)
{
    const int g   = blockIdx.x;
    const int tid = threadIdx.x;
    __shared__ float Sn[64 * 68];
    __shared__ float Pm[64 * 68];
    __shared__ float T1[64 * 68];
    __shared__ float T2[64 * 68];
    __shared__ float lmean[64];
    __shared__ float redm[1024];
    __shared__ float rtr_s;

    if (tid < 64) lmean[tid] = Mean[g * 64 + tid];
    __syncthreads();
    for (int idx = tid; idx < 4096; idx += 256) {
        int d = idx >> 6, e = idx & 63;
        float v = Gram[g * 4096 + idx] * (1.0f / (float)MTOT) - lmean[d] * lmean[e];
        if (d == e) v += EPSV;
        Sn[d * 68 + e] = v;
        Pm[d * 68 + e] = (d == e) ? 1.f : 0.f;
    }
    __syncthreads();
    if (tid < 64) {
        float v = Sn[tid * 68 + tid];
#pragma unroll
        for (int off = 32; off > 0; off >>= 1) v += __shfl_down(v, off);
        if (tid == 0) rtr_s = 1.f / v;
    }
    __syncthreads();
    const float rTr = rtr_s;
    for (int idx = tid; idx < 4096; idx += 256) {
        int d = idx >> 6, e = idx & 63;
        Sn[d * 68 + e] *= rTr;
    }
    __syncthreads();

    const int i0 = (tid >> 4) << 2, j0 = (tid & 15) << 2;
    for (int it = 0; it < 5; ++it) {
        mm64<0>(T1, Pm, Pm, i0, j0); __syncthreads();
        mm64<0>(T2, T1, Pm, i0, j0); __syncthreads();
        mm64<1>(Pm, T2, Sn, i0, j0); __syncthreads();
    }

    const float sc = sqrtf(rTr);
#pragma unroll
    for (int i = 0; i < 4; ++i) {
        int d = i0 + i;
        float wv = Wt[g * 64 + d] * sc;
        float4 v;
        v.x = Pm[d * 68 + j0 + 0] * wv;
        v.y = Pm[d * 68 + j0 + 1] * wv;
        v.z = Pm[d * 68 + j0 + 2] * wv;
        v.w = Pm[d * 68 + j0 + 3] * wv;
        *reinterpret_cast<float4*>(Aout + g * 4096 + (d << 6) + j0) = v;
        redm[(d << 4) + (tid & 15)] =
            v.x * lmean[j0] + v.y * lmean[j0 + 1] + v.z * lmean[j0 + 2] + v.w * lmean[j0 + 3];
    }
    __syncthreads();
    if (tid < 64) {
        float s = 0.f;
#pragma unroll
        for (int qq = 0; qq < 16; ++qq) s += redm[(tid << 4) + qq];
        Off[g * 64 + tid] = Bs[g * 64 + tid] - s;
    }
}

// ---------------------------------------------------------------------------
// K3: out = A'(x) + off via hi/lo MFMA. MFMA column-group j covers cols
// 4*lane+j (col-sets mod 4) -> dwordx4 loads AND stores of 4 consecutive
// cols per lane (256B/instr per 16-lane group). 64-col chunks (HW%64==0).
// ---------------------------------------------------------------------------
__global__ __launch_bounds__(256) void k3_apply(const float* __restrict__ X,
                                                const float* __restrict__ Aout,
                                                const float* __restrict__ Off,
                                                float* __restrict__ Y)
{
    const int bx   = blockIdx.x;        // 0..391
    const int g    = blockIdx.y;
    const int tid  = threadIdx.x;
    const int w    = tid >> 6;          // output row block 16w
    const int lane = tid & 63;
    const int lr   = lane & 15;
    const int q    = lane >> 4;

    // A' fragments (2 ksteps x hi/lo), loaded once; lane lr = output row
    bf16x8 ah[2], al[2];
#pragma unroll
    for (int s = 0; s < 2; ++s) {
        const float* ap = Aout + g * 4096 + (16 * w + lr) * 64 + 32 * s + 8 * q;
        float4 v0 = *reinterpret_cast<const float4*>(ap);
        float4 v1 = *reinterpret_cast<const float4*>(ap + 4);
        float av[8] = {v0.x, v0.y, v0.z, v0.w, v1.x, v1.y, v1.z, v1.w};
#pragma unroll
        for (int j = 0; j < 8; ++j) {
            short h, l; split2(av[j], h, l);
            ah[s][j] = h; al[s][j] = l;
        }
    }
    float offv[4];
#pragma unroll
    for (int r = 0; r < 4; ++r) offv[r] = Off[g * 64 + 16 * w + 4 * q + r];

    const float* Xg = X + (size_t)g * DCH * HW;
    float*       Yg = Y + (size_t)g * DCH * HW;

    for (int c = bx; c < MTOT / 64; c += 392) {
        const int col0 = c * 64;            // 64-col chunk, never crosses sample
        const int n    = col0 / HW;
        const int s0   = col0 - n * HW;
        const float* base = Xg + (size_t)n * CHW + s0 + 4 * lr;

        f32x4 accg[4];
#pragma unroll
        for (int j = 0; j < 4; ++j) accg[j] = (f32x4)(0.f);

#pragma unroll
        for (int ks = 0; ks < 2; ++ks) {
            bf16x8 bh[4], bl[4];
#pragma unroll
            for (int j8 = 0; j8 < 8; ++j8) {
                const float* xp = base + (size_t)(32 * ks + 8 * q + j8) * HW;
                float4 v = *reinterpret_cast<const float4*>(xp);
                float vv[4] = {v.x, v.y, v.z, v.w};
#pragma unroll
                for (int jj = 0; jj < 4; ++jj) {
                    short h, l; split2(vv[jj], h, l);
                    bh[jj][j8] = h; bl[jj][j8] = l;
                }
            }
#pragma unroll
            for (int jj = 0; jj < 4; ++jj) {
                accg[jj] = mfma16(ah[ks], bh[jj], accg[jj]);
                accg[jj] = mfma16(ah[ks], bl[jj], accg[jj]);
                accg[jj] = mfma16(al[ks], bh[jj], accg[jj]);
            }
        }
        float* yp = Yg + (size_t)n * CHW + s0 + 4 * lr;
#pragma unroll
        for (int r = 0; r < 4; ++r) {
            int row = 16 * w + 4 * q + r;
            float4 o;
            o.x = accg[0][r] + offv[r];
            o.y = accg[1][r] + offv[r];
            o.z = accg[2][r] + offv[r];
            o.w = accg[3][r] + offv[r];
            *reinterpret_cast<float4*>(yp + (size_t)row * HW) = o;
        }
    }
}

// ---------------------------------------------------------------------------
extern "C" void kernel_launch(void* const* d_in, const int* in_sizes, int n_in,
                              void* d_out, int out_size, void* d_ws, size_t ws_size,
                              hipStream_t stream)
{
    const float* X  = (const float*)d_in[0];
    const float* Wt = (const float*)d_in[1];
    const float* Bs = (const float*)d_in[2];
    float* Y  = (float*)d_out;
    float* ws = (float*)d_ws;

    float* pGram = ws;                                   // 4*PB*4096
    float* pSum  = pGram + (size_t)4 * PB * 4096;        // 4*PB*64
    float* Gram  = pSum  + (size_t)4 * PB * 64;          // 4*4096
    float* Mean  = Gram  + 4 * 4096;                     // 256
    float* Aout  = Mean  + 256;                          // 4*4096
    float* Off   = Aout  + 4 * 4096;                     // 256

    k1_gram   <<<dim3(PB, GROUPS), 512, 0, stream>>>(X, pGram, pSum);
    k2a_reduce<<<dim3(64, GROUPS), 256, 0, stream>>>(pGram, pSum, Gram, Mean);
    k2b_ns    <<<dim3(GROUPS), 256, 0, stream>>>(Gram, Mean, Wt, Bs, Aout, Off);
    k3_apply  <<<dim3(392, GROUPS), 256, 0, stream>>>(X, Aout, Off, Y);
}